// Round 8
// baseline (106.596 us; speedup 1.0000x reference)
//
#include <hip/hip_runtime.h>

// ContactMapHead on MI355X — round 5 kernel, resubmit #3 (broker timeouts; never benched).
// 4x4 micro-tiles (halve LDS ops per FMA), bias-init folded into gemm prologue.
// logits[b, p(i,j)] = h_i^T W h_j + b, p(i,j) = i*(1023-i)/2 + (j-i-1).
//
//   K1 gemm_g: out[:]=bias prologue, then G[b] = H[b] @ W
//              (256 blocks x 128 thr, tile 32m x 64n, micro 4x4)
//   K2 pair:   out += triu(G[b] @ H[b]^T)
//              (576 blocks: 72 triu-tiles x 2 b x 4 ksplit, atomicAdd partials)

#define LSEQ 512
#define HDIM 512
#define NPAIR 130816     // 512*511/2
#define KT 32
#define PADA 36          // 36*4 = 144 B row stride (multiple of 16 -> b128-aligned)
#define PADH 68          // 68*4 = 272 B row stride (multiple of 16)

// ---------------- K1: out=bias prologue + G = H @ W ----------------
__global__ __launch_bounds__(128)
void gemm_g(const float* __restrict__ hid, const float* __restrict__ W,
            const float* __restrict__ bias, float* __restrict__ G,
            float* __restrict__ out) {
    // bias prologue: 256 blocks x 128 thr cover 65408 float4 in 2 grid-strides
    {
        const int bid = (blockIdx.z * 16 + blockIdx.y) * 8 + blockIdx.x;
        const float bb = bias[0];
        const float4 v = make_float4(bb, bb, bb, bb);
        for (int i = bid * 128 + threadIdx.x; i < (2 * NPAIR) / 4; i += 256 * 128)
            ((float4*)out)[i] = v;
    }

    __shared__ float As[KT][PADA];   // k-major: As[k][m']
    __shared__ float Bs[KT][64];     // k-major: Bs[k][n'] (natural from W rows)
    const int b  = blockIdx.z;
    const int m0 = blockIdx.y * 32;
    const int n0 = blockIdx.x * 64;
    const int t  = threadIdx.x;
    const int tx = t & 15, ty = t >> 4;     // tx: 4 cols of 64, ty: 4 rows of 32
    const float* A = hid + b * (LSEQ * HDIM);

    float acc[4][4] = {};
    for (int k0 = 0; k0 < HDIM; k0 += KT) {
        #pragma unroll
        for (int l = 0; l < 2; ++l) {        // stage A: 32x32, transpose to k-major
            const int idx = t + l * 128;
            const int r = idx >> 3, c4 = (idx & 7) << 2;
            float4 va = *(const float4*)&A[(m0 + r) * HDIM + k0 + c4];
            As[c4 + 0][r] = va.x; As[c4 + 1][r] = va.y;
            As[c4 + 2][r] = va.z; As[c4 + 3][r] = va.w;
        }
        #pragma unroll
        for (int l = 0; l < 4; ++l) {        // stage B: 32 k-rows x 64 n
            const int idx = t + l * 128;
            const int r = idx >> 4, c4 = (idx & 15) << 2;
            *(float4*)&Bs[r][c4] = *(const float4*)&W[(k0 + r) * HDIM + n0 + c4];
        }
        __syncthreads();
        #pragma unroll
        for (int kk = 0; kk < KT; ++kk) {
            const float4 av = *(const float4*)&As[kk][ty << 2];
            const float4 bv = *(const float4*)&Bs[kk][tx << 2];
            const float a[4] = {av.x, av.y, av.z, av.w};
            const float w4[4] = {bv.x, bv.y, bv.z, bv.w};
            #pragma unroll
            for (int i = 0; i < 4; ++i)
                #pragma unroll
                for (int j = 0; j < 4; ++j)
                    acc[i][j] += a[i] * w4[j];
        }
        __syncthreads();
    }
    float* Gb = G + b * (LSEQ * HDIM);
    #pragma unroll
    for (int i = 0; i < 4; ++i)
        *(float4*)&Gb[(m0 + (ty << 2) + i) * HDIM + n0 + (tx << 2)] =
            make_float4(acc[i][0], acc[i][1], acc[i][2], acc[i][3]);
}

// ---------------- K2: out += triu(G @ H^T), tile 32i x 64j, micro 4x4, K-split 4 ----------------
__global__ __launch_bounds__(128)
void pair(const float* __restrict__ G, const float* __restrict__ hid,
          float* __restrict__ out) {
    __shared__ float Gs[KT][PADA];   // k-major: Gs[k][i']
    __shared__ float Hs[KT][PADH];   // k-major: Hs[k][j']
    const int b = blockIdx.y;
    const int s = blockIdx.z;                    // k-split slice (K=128 each)
    // map bid 0..71 -> (bi 0..15, bj (bi>>1)..7): 32-row i-tile, 64-col j-tile
    int rem = blockIdx.x, bi = 0;
    while (rem >= 8 - (bi >> 1)) { rem -= 8 - (bi >> 1); ++bi; }
    const int bj = (bi >> 1) + rem;
    const int i0 = bi * 32, j0 = bj * 64;
    const int t  = threadIdx.x;
    const int tx = t & 15, ty = t >> 4;
    const float* Gb = G   + b * (LSEQ * HDIM);
    const float* Hb = hid + b * (LSEQ * HDIM);

    float acc[4][4] = {};
    for (int k0 = s * 128; k0 < s * 128 + 128; k0 += KT) {
        #pragma unroll
        for (int l = 0; l < 2; ++l) {        // stage G: 32 rows x 32 k
            const int idx = t + l * 128;
            const int r = idx >> 3, c4 = (idx & 7) << 2;
            float4 vg = *(const float4*)&Gb[(i0 + r) * HDIM + k0 + c4];
            Gs[c4 + 0][r] = vg.x; Gs[c4 + 1][r] = vg.y;
            Gs[c4 + 2][r] = vg.z; Gs[c4 + 3][r] = vg.w;
        }
        #pragma unroll
        for (int l = 0; l < 4; ++l) {        // stage H: 64 rows x 32 k, transpose
            const int idx = t + l * 128;
            const int r = idx >> 3, c4 = (idx & 7) << 2;
            float4 vh = *(const float4*)&Hb[(j0 + r) * HDIM + k0 + c4];
            Hs[c4 + 0][r] = vh.x; Hs[c4 + 1][r] = vh.y;
            Hs[c4 + 2][r] = vh.z; Hs[c4 + 3][r] = vh.w;
        }
        __syncthreads();
        #pragma unroll
        for (int kk = 0; kk < KT; ++kk) {
            const float4 gv = *(const float4*)&Gs[kk][ty << 2];
            const float4 hv = *(const float4*)&Hs[kk][tx << 2];
            const float g[4] = {gv.x, gv.y, gv.z, gv.w};
            const float h[4] = {hv.x, hv.y, hv.z, hv.w};
            #pragma unroll
            for (int i = 0; i < 4; ++i)
                #pragma unroll
                for (int j = 0; j < 4; ++j)
                    acc[i][j] += g[i] * h[j];
        }
        __syncthreads();
    }

    float* ob = out + b * NPAIR;
    #pragma unroll
    for (int ii = 0; ii < 4; ++ii) {
        const int i = i0 + (ty << 2) + ii;
        const int rowbase = (i * (1023 - i)) >> 1;
        const int jb = j0 + (tx << 2);
        #pragma unroll
        for (int jj = 0; jj < 4; ++jj) {
            const int j = jb + jj;
            if (j > i) atomicAdd(&ob[rowbase + j - i - 1], acc[ii][jj]);
        }
    }
}

extern "C" void kernel_launch(void* const* d_in, const int* in_sizes, int n_in,
                              void* d_out, int out_size, void* d_ws, size_t ws_size,
                              hipStream_t stream) {
    const float* hid  = (const float*)d_in[0];   // (2, 512, 512) f32
    const float* W    = (const float*)d_in[1];   // (1, 512, 512) f32
    const float* bias = (const float*)d_in[2];   // (1,) f32
    float* out = (float*)d_out;                  // (2, 130816) f32
    float* G   = (float*)d_ws;                   // 2 MB scratch

    gemm_g<<<dim3(8, 16, 2), 128, 0, stream>>>(hid, W, bias, G, out);
    pair<<<dim3(72, 2, 4), 128, 0, stream>>>(G, hid, out);
}

// Round 11
// 101.603 us; speedup vs baseline: 1.0491x; 1.0491x over previous
//
#include <hip/hip_runtime.h>

// ContactMapHead on MI355X — round 9 kernel, resubmit #2 (broker timeouts; never benched).
// Round-8 lesson: 128thr x 256 blocks = 2 waves/CU = half the SIMDs idle.
// Fix: gemm K-split 2 into disjoint buffers G0/G1 (512 blocks, 4 waves/CU, no
// atomics); pair (round-4 proven shape) sums G0+G1 during staging.
// logits[b, p(i,j)] = h_i^T W h_j + b, p(i,j) = i*(1023-i)/2 + (j-i-1).
//
//   K1 gemm_g: out[:]=bias prologue; Gs[b] = H[b] @ W (K-half s)
//              (512 blocks x 128 thr: 8n x 16m x (2b x 2s), tile 32m x 64n, micro 4x4)
//   K2 pair:   out += triu((G0[b]+G1[b]) @ H[b]^T)
//              (576 blocks x 256 thr: 72 triu-tiles x 2b x 4 ksplit, atomicAdd)

#define LSEQ 512
#define HDIM 512
#define NPAIR 130816     // 512*511/2
#define KT 32
#define PADA 36          // 36*4 = 144 B row stride (16B-aligned for b128)
#define PADH 68          // 68*4 = 272 B row stride (16B-aligned)
#define GELEMS (2 * LSEQ * HDIM)   // floats per G buffer

// ---------------- K1: out=bias prologue + G[s][b] = H[b] @ W (K-half s) ----------------
__global__ __launch_bounds__(128)
void gemm_g(const float* __restrict__ hid, const float* __restrict__ W,
            const float* __restrict__ bias, float* __restrict__ G01,
            float* __restrict__ out) {
    // bias prologue: 512 blocks x 128 thr = 65536 threads cover 65408 float4
    {
        const int bid = (blockIdx.z * 16 + blockIdx.y) * 8 + blockIdx.x;
        const int i = bid * 128 + threadIdx.x;
        const float bb = bias[0];
        if (i < (2 * NPAIR) / 4)
            ((float4*)out)[i] = make_float4(bb, bb, bb, bb);
    }

    __shared__ float As[KT][PADA];   // k-major: As[k][m']
    __shared__ float Bs[KT][64];     // k-major: Bs[k][n'] (natural from W rows)
    const int b  = blockIdx.z >> 1;          // batch
    const int s  = blockIdx.z & 1;           // K-half: k in [s*256, s*256+256)
    const int m0 = blockIdx.y * 32;
    const int n0 = blockIdx.x * 64;
    const int t  = threadIdx.x;
    const int tx = t & 15, ty = t >> 4;      // 16 x 8 thread grid, 4x4 micro
    const float* A = hid + b * (LSEQ * HDIM);

    float acc[4][4] = {};
    for (int k0 = s * 256; k0 < s * 256 + 256; k0 += KT) {
        #pragma unroll
        for (int l = 0; l < 2; ++l) {        // stage A: 32 rows x 32 k, transpose
            const int idx = t + l * 128;
            const int r = idx >> 3, c4 = (idx & 7) << 2;
            float4 va = *(const float4*)&A[(m0 + r) * HDIM + k0 + c4];
            As[c4 + 0][r] = va.x; As[c4 + 1][r] = va.y;
            As[c4 + 2][r] = va.z; As[c4 + 3][r] = va.w;
        }
        #pragma unroll
        for (int l = 0; l < 4; ++l) {        // stage B: 32 k-rows x 64 n
            const int idx = t + l * 128;
            const int r = idx >> 4, c4 = (idx & 15) << 2;
            *(float4*)&Bs[r][c4] = *(const float4*)&W[(k0 + r) * HDIM + n0 + c4];
        }
        __syncthreads();
        #pragma unroll
        for (int kk = 0; kk < KT; ++kk) {
            const float4 av = *(const float4*)&As[kk][ty << 2];
            const float4 bv = *(const float4*)&Bs[kk][tx << 2];
            const float a[4] = {av.x, av.y, av.z, av.w};
            const float w4[4] = {bv.x, bv.y, bv.z, bv.w};
            #pragma unroll
            for (int i = 0; i < 4; ++i)
                #pragma unroll
                for (int j = 0; j < 4; ++j)
                    acc[i][j] += a[i] * w4[j];
        }
        __syncthreads();
    }
    float* Gp = G01 + s * GELEMS + b * (LSEQ * HDIM);
    #pragma unroll
    for (int i = 0; i < 4; ++i)
        *(float4*)&Gp[(m0 + (ty << 2) + i) * HDIM + n0 + (tx << 2)] =
            make_float4(acc[i][0], acc[i][1], acc[i][2], acc[i][3]);
}

// ---------------- K2: out += triu((G0+G1) @ H^T), tile 32i x 64j, micro 2x4, ksplit 4 ----------------
__global__ __launch_bounds__(256)
void pair(const float* __restrict__ G01, const float* __restrict__ hid,
          float* __restrict__ out) {
    __shared__ float Gs[KT][PADA];   // k-major: Gs[k][i']
    __shared__ float Hs[KT][PADH];   // k-major: Hs[k][j']
    const int b = blockIdx.y;
    const int s = blockIdx.z;                    // k-split slice (K=128 each)
    // map bid 0..71 -> (bi 0..15, bj (bi>>1)..7): 32-row i-tile, 64-col j-tile
    int rem = blockIdx.x, bi = 0;
    while (rem >= 8 - (bi >> 1)) { rem -= 8 - (bi >> 1); ++bi; }
    const int bj = (bi >> 1) + rem;
    const int i0 = bi * 32, j0 = bj * 64;
    const int t  = threadIdx.x;
    const int tx = t & 15, ty = t >> 4;
    const float* Gb0 = G01 + b * (LSEQ * HDIM);            // K-half 0 partial
    const float* Gb1 = G01 + GELEMS + b * (LSEQ * HDIM);   // K-half 1 partial
    const float* Hb  = hid + b * (LSEQ * HDIM);

    float acc[2][4] = {};
    for (int k0 = s * 128; k0 < s * 128 + 128; k0 += KT) {
        {   // stage G = G0+G1: 32 rows x 32 k = 256 float4, transpose to k-major
            const int r = t >> 3, c4 = (t & 7) << 2;
            const int off = (i0 + r) * HDIM + k0 + c4;
            float4 v0 = *(const float4*)&Gb0[off];
            float4 v1 = *(const float4*)&Gb1[off];
            Gs[c4 + 0][r] = v0.x + v1.x; Gs[c4 + 1][r] = v0.y + v1.y;
            Gs[c4 + 2][r] = v0.z + v1.z; Gs[c4 + 3][r] = v0.w + v1.w;
        }
        #pragma unroll
        for (int l = 0; l < 2; ++l) {  // stage H: 64 rows x 32 k, transpose
            const int idx = t + l * 256;
            const int r = idx >> 3, c4 = (idx & 7) << 2;
            float4 vh = *(const float4*)&Hb[(j0 + r) * HDIM + k0 + c4];
            Hs[c4 + 0][r] = vh.x; Hs[c4 + 1][r] = vh.y;
            Hs[c4 + 2][r] = vh.z; Hs[c4 + 3][r] = vh.w;
        }
        __syncthreads();
        #pragma unroll
        for (int kk = 0; kk < KT; ++kk) {
            const float2 gv = *(const float2*)&Gs[kk][ty << 1];
            const float4 hv = *(const float4*)&Hs[kk][tx << 2];
            const float g[2] = {gv.x, gv.y};
            const float h[4] = {hv.x, hv.y, hv.z, hv.w};
            #pragma unroll
            for (int i = 0; i < 2; ++i)
                #pragma unroll
                for (int j = 0; j < 4; ++j)
                    acc[i][j] += g[i] * h[j];
        }
        __syncthreads();
    }

    float* ob = out + b * NPAIR;
    #pragma unroll
    for (int ii = 0; ii < 2; ++ii) {
        const int i = i0 + (ty << 1) + ii;
        const int rowbase = (i * (1023 - i)) >> 1;
        const int jb = j0 + (tx << 2);
        #pragma unroll
        for (int jj = 0; jj < 4; ++jj) {
            const int j = jb + jj;
            if (j > i) atomicAdd(&ob[rowbase + j - i - 1], acc[ii][jj]);
        }
    }
}

extern "C" void kernel_launch(void* const* d_in, const int* in_sizes, int n_in,
                              void* d_out, int out_size, void* d_ws, size_t ws_size,
                              hipStream_t stream) {
    const float* hid  = (const float*)d_in[0];   // (2, 512, 512) f32
    const float* W    = (const float*)d_in[1];   // (1, 512, 512) f32
    const float* bias = (const float*)d_in[2];   // (1,) f32
    float* out = (float*)d_out;                  // (2, 130816) f32
    float* G01 = (float*)d_ws;                   // G0 (2MB) + G1 (2MB) scratch

    gemm_g<<<dim3(8, 16, 4), 128, 0, stream>>>(hid, W, bias, G01, out);
    pair<<<dim3(72, 2, 4), 256, 0, stream>>>(G01, hid, out);
}

// Round 13
// 97.467 us; speedup vs baseline: 1.0937x; 1.0424x over previous
//
#include <hip/hip_runtime.h>

// ContactMapHead on MI355X — round 12 kernel, resubmit (broker timeout; never benched).
// gemm K-split 4 (8 waves/CU, 2 waves/SIMD). r8→r11 confirmed SIMD-occupancy is the
// lever: 2 waves/CU idles half the SIMDs, 4 waves/CU = 1 wave/SIMD still exposes LDS
// latency. This round: 1024 gemm blocks = 4 blocks/CU = 2 waves/SIMD. Pair (proven
// r11 shape) sums 4 G-partials in staging.
// logits[b, p(i,j)] = h_i^T W h_j + b, p(i,j) = i*(1023-i)/2 + (j-i-1).
//
//   K1 gemm_g: out[:]=bias prologue; G[s][b] = H[b] @ W (K-quarter s)
//              (1024 blocks x 128 thr: 8n x 16m x (2b x 4s), tile 32m x 64n, micro 4x4)
//   K2 pair:   out += triu((G0+G1+G2+G3)[b] @ H[b]^T)
//              (576 blocks x 256 thr: 72 triu-tiles x 2b x 4 ksplit, atomicAdd)

#define LSEQ 512
#define HDIM 512
#define NPAIR 130816     // 512*511/2
#define KT 32
#define PADA 36          // 36*4 = 144 B row stride (16B-aligned for b128)
#define PADH 68          // 68*4 = 272 B row stride (16B-aligned)
#define GELEMS (2 * LSEQ * HDIM)   // floats per G partial buffer (both batches)

// ---------------- K1: out=bias prologue + G[s][b] = H[b] @ W (K-quarter s) ----------------
__global__ __launch_bounds__(128)
void gemm_g(const float* __restrict__ hid, const float* __restrict__ W,
            const float* __restrict__ bias, float* __restrict__ G4,
            float* __restrict__ out) {
    // bias prologue: 1024 blocks x 128 thr = 131072 threads cover 65408 float4
    {
        const int bid = (blockIdx.z * 16 + blockIdx.y) * 8 + blockIdx.x;
        const int i = bid * 128 + threadIdx.x;
        if (i < (2 * NPAIR) / 4) {
            const float bb = bias[0];
            ((float4*)out)[i] = make_float4(bb, bb, bb, bb);
        }
    }

    __shared__ float As[KT][PADA];   // k-major: As[k][m']
    __shared__ float Bs[KT][64];     // k-major: Bs[k][n'] (natural from W rows)
    const int b  = blockIdx.z >> 2;          // batch
    const int s  = blockIdx.z & 3;           // K-quarter: k in [s*128, s*128+128)
    const int m0 = blockIdx.y * 32;
    const int n0 = blockIdx.x * 64;
    const int t  = threadIdx.x;
    const int tx = t & 15, ty = t >> 4;      // 16 x 8 thread grid, 4x4 micro
    const float* A = hid + b * (LSEQ * HDIM);

    float acc[4][4] = {};
    for (int k0 = s * 128; k0 < s * 128 + 128; k0 += KT) {
        #pragma unroll
        for (int l = 0; l < 2; ++l) {        // stage A: 32 rows x 32 k, transpose
            const int idx = t + l * 128;
            const int r = idx >> 3, c4 = (idx & 7) << 2;
            float4 va = *(const float4*)&A[(m0 + r) * HDIM + k0 + c4];
            As[c4 + 0][r] = va.x; As[c4 + 1][r] = va.y;
            As[c4 + 2][r] = va.z; As[c4 + 3][r] = va.w;
        }
        #pragma unroll
        for (int l = 0; l < 4; ++l) {        // stage B: 32 k-rows x 64 n
            const int idx = t + l * 128;
            const int r = idx >> 4, c4 = (idx & 15) << 2;
            *(float4*)&Bs[r][c4] = *(const float4*)&W[(k0 + r) * HDIM + n0 + c4];
        }
        __syncthreads();
        #pragma unroll
        for (int kk = 0; kk < KT; ++kk) {
            const float4 av = *(const float4*)&As[kk][ty << 2];
            const float4 bv = *(const float4*)&Bs[kk][tx << 2];
            const float a[4] = {av.x, av.y, av.z, av.w};
            const float w4[4] = {bv.x, bv.y, bv.z, bv.w};
            #pragma unroll
            for (int i = 0; i < 4; ++i)
                #pragma unroll
                for (int j = 0; j < 4; ++j)
                    acc[i][j] += a[i] * w4[j];
        }
        __syncthreads();
    }
    float* Gp = G4 + s * GELEMS + b * (LSEQ * HDIM);
    #pragma unroll
    for (int i = 0; i < 4; ++i)
        *(float4*)&Gp[(m0 + (ty << 2) + i) * HDIM + n0 + (tx << 2)] =
            make_float4(acc[i][0], acc[i][1], acc[i][2], acc[i][3]);
}

// ---------------- K2: out += triu((ΣG)[b] @ H^T), tile 32i x 64j, micro 2x4, ksplit 4 ----------------
__global__ __launch_bounds__(256)
void pair(const float* __restrict__ G4, const float* __restrict__ hid,
          float* __restrict__ out) {
    __shared__ float Gs[KT][PADA];   // k-major: Gs[k][i']
    __shared__ float Hs[KT][PADH];   // k-major: Hs[k][j']
    const int b = blockIdx.y;
    const int s = blockIdx.z;                    // k-split slice (K=128 each)
    // map bid 0..71 -> (bi 0..15, bj (bi>>1)..7): 32-row i-tile, 64-col j-tile
    int rem = blockIdx.x, bi = 0;
    while (rem >= 8 - (bi >> 1)) { rem -= 8 - (bi >> 1); ++bi; }
    const int bj = (bi >> 1) + rem;
    const int i0 = bi * 32, j0 = bj * 64;
    const int t  = threadIdx.x;
    const int tx = t & 15, ty = t >> 4;
    const float* Gb0 = G4 + 0 * GELEMS + b * (LSEQ * HDIM);
    const float* Gb1 = G4 + 1 * GELEMS + b * (LSEQ * HDIM);
    const float* Gb2 = G4 + 2 * GELEMS + b * (LSEQ * HDIM);
    const float* Gb3 = G4 + 3 * GELEMS + b * (LSEQ * HDIM);
    const float* Hb  = hid + b * (LSEQ * HDIM);

    float acc[2][4] = {};
    for (int k0 = s * 128; k0 < s * 128 + 128; k0 += KT) {
        {   // stage G = G0+G1+G2+G3: 32 rows x 32 k = 256 float4, transpose to k-major
            const int r = t >> 3, c4 = (t & 7) << 2;
            const int off = (i0 + r) * HDIM + k0 + c4;
            float4 v0 = *(const float4*)&Gb0[off];
            float4 v1 = *(const float4*)&Gb1[off];
            float4 v2 = *(const float4*)&Gb2[off];
            float4 v3 = *(const float4*)&Gb3[off];
            Gs[c4 + 0][r] = (v0.x + v1.x) + (v2.x + v3.x);
            Gs[c4 + 1][r] = (v0.y + v1.y) + (v2.y + v3.y);
            Gs[c4 + 2][r] = (v0.z + v1.z) + (v2.z + v3.z);
            Gs[c4 + 3][r] = (v0.w + v1.w) + (v2.w + v3.w);
        }
        #pragma unroll
        for (int l = 0; l < 2; ++l) {  // stage H: 64 rows x 32 k, transpose
            const int idx = t + l * 256;
            const int r = idx >> 3, c4 = (idx & 7) << 2;
            float4 vh = *(const float4*)&Hb[(j0 + r) * HDIM + k0 + c4];
            Hs[c4 + 0][r] = vh.x; Hs[c4 + 1][r] = vh.y;
            Hs[c4 + 2][r] = vh.z; Hs[c4 + 3][r] = vh.w;
        }
        __syncthreads();
        #pragma unroll
        for (int kk = 0; kk < KT; ++kk) {
            const float2 gv = *(const float2*)&Gs[kk][ty << 1];
            const float4 hv = *(const float4*)&Hs[kk][tx << 2];
            const float g[2] = {gv.x, gv.y};
            const float h[4] = {hv.x, hv.y, hv.z, hv.w};
            #pragma unroll
            for (int i = 0; i < 2; ++i)
                #pragma unroll
                for (int j = 0; j < 4; ++j)
                    acc[i][j] += g[i] * h[j];
        }
        __syncthreads();
    }

    float* ob = out + b * NPAIR;
    #pragma unroll
    for (int ii = 0; ii < 2; ++ii) {
        const int i = i0 + (ty << 1) + ii;
        const int rowbase = (i * (1023 - i)) >> 1;
        const int jb = j0 + (tx << 2);
        #pragma unroll
        for (int jj = 0; jj < 4; ++jj) {
            const int j = jb + jj;
            if (j > i) atomicAdd(&ob[rowbase + j - i - 1], acc[ii][jj]);
        }
    }
}

extern "C" void kernel_launch(void* const* d_in, const int* in_sizes, int n_in,
                              void* d_out, int out_size, void* d_ws, size_t ws_size,
                              hipStream_t stream) {
    const float* hid  = (const float*)d_in[0];   // (2, 512, 512) f32
    const float* W    = (const float*)d_in[1];   // (1, 512, 512) f32
    const float* bias = (const float*)d_in[2];   // (1,) f32
    float* out = (float*)d_out;                  // (2, 130816) f32
    float* G4  = (float*)d_ws;                   // 4 x 2MB G partials

    gemm_g<<<dim3(8, 16, 8), 128, 0, stream>>>(hid, W, bias, G4, out);
    pair<<<dim3(72, 2, 4), 256, 0, stream>>>(G4, hid, out);
}